// Round 8
// baseline (237.272 us; speedup 1.0000x reference)
//
#include <hip/hip_runtime.h>

// Derivative1D: y[b, i, c] = x[b, i+1, c] - x[b, i, c]
// x: (B=64, L=16384, C=32) fp32 contiguous; y: (B, L-1, C) fp32.
// Flattened per batch: out[r] = x[r + C] - x[r], r in [0, (L-1)*C).
//
// V6: persistent grid-stride (m13 copy structure, 2048 blocks = 8/CU,
//     16 iters/thread, 1-deep rotate prefetch) + V5's shuffle dedupe of
//     the second read stream (n[lane] = a[lane+8] within the wave; only
//     lanes 56-63 do a real 16B halo load).
//     Completes the 2x2 matrix: V3 oneshot+dup=80us, V4 persist+dup=82us,
//     V5 oneshot+dedupe=best(217.8 total), V6 persist+dedupe=?
//     V4's null result was confounded by the duplicated read stream.

typedef float f32x4 __attribute__((ext_vector_type(4)));

constexpr int B = 64;
constexpr int L = 16384;
constexpr int C = 32;
constexpr int PER_BATCH    = (L - 1) * C;      // 524256 floats per batch (out)
constexpr int PER_BATCH_V4 = PER_BATCH / 4;    // 131064 float4 per batch (exact)
constexpr int IN_PER_BATCH = L * C;            // 524288 floats per batch (in)

constexpr int BLOCK  = 256;
constexpr int GX     = 32;                     // 32*64 = 2048 blocks = 8/CU
constexpr int STRIDE = GX * BLOCK;             // 8192 float4 per sweep
constexpr int ITERS  = (PER_BATCH_V4 + STRIDE - 1) / STRIDE;   // 16 (last partial)

__global__ __launch_bounds__(BLOCK) void deriv1d_kernel(const float* __restrict__ x,
                                                        float* __restrict__ out) {
    const int b    = blockIdx.y;
    const int lane = threadIdx.x & 63;
    const float* xb = x   + (size_t)b * IN_PER_BATCH;
    float*       ob = out + (size_t)b * PER_BATCH;

    int i = blockIdx.x * BLOCK + threadIdx.x;  // float4 index within batch

    // Prologue: iteration-0 loads.
    // a-load is ALWAYS safe: max i over all iters = 131071 -> floats
    // [524284, 524288) = exactly the end of the batch.
    f32x4 a = *reinterpret_cast<const f32x4*>(xb + (size_t)i * 4);
    f32x4 h;
    if (lane >= 56 && i < PER_BATCH_V4) {
        h = *reinterpret_cast<const f32x4*>(xb + (size_t)i * 4 + C);
    }

#pragma unroll
    for (int it = 0; it < ITERS; ++it) {
        // Issue next iteration's loads first (independent of current compute).
        const int inext = i + STRIDE;
        f32x4 a2, h2;
        if (it + 1 < ITERS) {
            a2 = *reinterpret_cast<const f32x4*>(xb + (size_t)inext * 4);
            if (lane >= 56 && inext < PER_BATCH_V4) {
                h2 = *reinterpret_cast<const f32x4*>(xb + (size_t)inext * 4 + C);
            }
        }

        // Current iteration: n = a from lane+8 (C = 8 float4 = 8 lanes).
        f32x4 n;
        n.x = __shfl_down(a.x, 8);
        n.y = __shfl_down(a.y, 8);
        n.z = __shfl_down(a.z, 8);
        n.w = __shfl_down(a.w, 8);
        if (lane >= 56) n = h;                 // wave-boundary halo

        if (i < PER_BATCH_V4) {
            *reinterpret_cast<f32x4*>(ob + (size_t)i * 4) = n - a;
        }

        i = inext; a = a2; h = h2;
    }
}

extern "C" void kernel_launch(void* const* d_in, const int* in_sizes, int n_in,
                              void* d_out, int out_size, void* d_ws, size_t ws_size,
                              hipStream_t stream) {
    const float* x = (const float*)d_in[0];
    float* out = (float*)d_out;

    dim3 grid(GX, B);      // 2048 blocks, 4 waves each = 32 waves/CU resident
    dim3 block(BLOCK);
    deriv1d_kernel<<<grid, block, 0, stream>>>(x, out);
}

// Round 9
// 220.852 us; speedup vs baseline: 1.0743x; 1.0743x over previous
//
#include <hip/hip_runtime.h>

// Derivative1D: y[b, i, c] = x[b, i+1, c] - x[b, i, c]
// x: (B=64, L=16384, C=32) fp32 contiguous; y: (B, L-1, C) fp32.
// Flattened per batch: out[r] = x[r + C] - x[r], r in [0, (L-1)*C).
//
// V7 = V5 (best, 217.8us total) + ONE change: nontemporal output stores.
//   Theory: FETCH is pinned at ~67MB = half the 134MB input across rounds.
//   The kernel's own write-allocations (131MB) push the L3 working set to
//   265MB > 256MB, evicting ~half the input each timed iteration. NT stores
//   keep the write-once output out of L3 -> input fully resident -> FETCH~0.
//   (V2b's neutral NT result was confounded with the ILP-4 regression.)
// Structure unchanged from V5: 1 float4/thread one-shot, 2D grid,
// shuffle-dedupe of the n-stream (n[lane] = a[lane+8], C = 8 float4 = 8 lanes;
// only lanes 56-63 do a real 16B halo load). No early return (shuffles).

typedef float f32x4 __attribute__((ext_vector_type(4)));

constexpr int B = 64;
constexpr int L = 16384;
constexpr int C = 32;
constexpr int PER_BATCH    = (L - 1) * C;      // 524256 floats per batch (out)
constexpr int PER_BATCH_V4 = PER_BATCH / 4;    // 131064 float4 per batch (exact)
constexpr int IN_PER_BATCH = L * C;            // 524288 floats per batch (in)

__global__ __launch_bounds__(256) void deriv1d_kernel(const float* __restrict__ x,
                                                      float* __restrict__ out) {
    const int r4   = blockIdx.x * 256 + threadIdx.x;   // float4 index within batch
    const int b    = blockIdx.y;
    const int lane = threadIdx.x & 63;

    const float* xb = x   + (size_t)b * IN_PER_BATCH;
    float*       ob = out + (size_t)b * PER_BATCH;

    // a-load is safe for ALL threads in the grid: max r4 = 131071 ->
    // floats [524284, 524288) which is exactly the end of the batch.
    const f32x4 a = *reinterpret_cast<const f32x4*>(xb + (size_t)r4 * 4);

    // n = a from lane+8 (same wave) for lanes 0..55.
    f32x4 n;
    n.x = __shfl_down(a.x, 8);
    n.y = __shfl_down(a.y, 8);
    n.z = __shfl_down(a.z, 8);
    n.w = __shfl_down(a.w, 8);

    // Lanes 56..63: neighbor is in the next wave's chunk -> direct halo load.
    if (lane >= 56 && r4 < PER_BATCH_V4) {
        n = *reinterpret_cast<const f32x4*>(xb + (size_t)r4 * 4 + C);
    }

    if (r4 < PER_BATCH_V4) {
        __builtin_nontemporal_store(n - a, reinterpret_cast<f32x4*>(ob + (size_t)r4 * 4));
    }
}

extern "C" void kernel_launch(void* const* d_in, const int* in_sizes, int n_in,
                              void* d_out, int out_size, void* d_ws, size_t ws_size,
                              hipStream_t stream) {
    const float* x = (const float*)d_in[0];
    float* out = (float*)d_out;

    // 131064 float4 per batch -> 512 blocks of 256 (tail predicated, not returned)
    dim3 grid((PER_BATCH_V4 + 255) / 256, B);
    dim3 block(256);
    deriv1d_kernel<<<grid, block, 0, stream>>>(x, out);
}

// Round 10
// 220.044 us; speedup vs baseline: 1.0783x; 1.0037x over previous
//
#include <hip/hip_runtime.h>

// Derivative1D: y[b, i, c] = x[b, i+1, c] - x[b, i, c]
// x: (B=64, L=16384, C=32) fp32 contiguous; y: (B, L-1, C) fp32.
// Flattened per batch: out[r] = x[r + C] - x[r], r in [0, (L-1)*C).
//
// V8 = V5 verbatim (best measured: 217.8us total). Final revert after the
// full lever matrix:
//   shuffle-dedupe of n-stream: -4.7us (the one win, kept)
//   ILP-4:            +7us   (V2b/V3)
//   persistent grid:  +5-20us (V4/V6)
//   nontemporal store: neutral/+3us (V2b/V7) -> L3-eviction theory dead
// Structure: 1 float4/thread one-shot, 2D grid; n[lane] = a[lane+8] via
// __shfl_down (C = 32 floats = 8 float4 = 8 lanes); only lanes 56-63 do a
// real 16B halo load. No early return (shuffles need all 64 lanes).

typedef float f32x4 __attribute__((ext_vector_type(4)));

constexpr int B = 64;
constexpr int L = 16384;
constexpr int C = 32;
constexpr int PER_BATCH    = (L - 1) * C;      // 524256 floats per batch (out)
constexpr int PER_BATCH_V4 = PER_BATCH / 4;    // 131064 float4 per batch (exact)
constexpr int IN_PER_BATCH = L * C;            // 524288 floats per batch (in)

__global__ __launch_bounds__(256) void deriv1d_kernel(const float* __restrict__ x,
                                                      float* __restrict__ out) {
    const int r4   = blockIdx.x * 256 + threadIdx.x;   // float4 index within batch
    const int b    = blockIdx.y;
    const int lane = threadIdx.x & 63;

    const float* xb = x   + (size_t)b * IN_PER_BATCH;
    float*       ob = out + (size_t)b * PER_BATCH;

    // a-load is safe for ALL threads in the grid: max r4 = 131071 ->
    // floats [524284, 524288) which is exactly the end of the batch.
    const f32x4 a = *reinterpret_cast<const f32x4*>(xb + (size_t)r4 * 4);

    // n = a from lane+8 (same wave) for lanes 0..55.
    f32x4 n;
    n.x = __shfl_down(a.x, 8);
    n.y = __shfl_down(a.y, 8);
    n.z = __shfl_down(a.z, 8);
    n.w = __shfl_down(a.w, 8);

    // Lanes 56..63: neighbor is in the next wave's chunk -> direct halo load.
    if (lane >= 56 && r4 < PER_BATCH_V4) {
        n = *reinterpret_cast<const f32x4*>(xb + (size_t)r4 * 4 + C);
    }

    if (r4 < PER_BATCH_V4) {
        *reinterpret_cast<f32x4*>(ob + (size_t)r4 * 4) = n - a;
    }
}

extern "C" void kernel_launch(void* const* d_in, const int* in_sizes, int n_in,
                              void* d_out, int out_size, void* d_ws, size_t ws_size,
                              hipStream_t stream) {
    const float* x = (const float*)d_in[0];
    float* out = (float*)d_out;

    // 131064 float4 per batch -> 512 blocks of 256 (tail predicated, not returned)
    dim3 grid((PER_BATCH_V4 + 255) / 256, B);
    dim3 block(256);
    deriv1d_kernel<<<grid, block, 0, stream>>>(x, out);
}